// Round 5
// baseline (377.702 us; speedup 1.0000x reference)
//
#include <hip/hip_runtime.h>

typedef __attribute__((ext_vector_type(8))) short bf16x8;
typedef __attribute__((ext_vector_type(4))) float f32x4;
typedef __attribute__((ext_vector_type(4))) unsigned short us4;
typedef unsigned short us;

#define SCALE 0.125f

__device__ __forceinline__ unsigned short f2bf(float f) {
    unsigned int u = __float_as_uint(f);
    u = (u + 0x7FFF + ((u >> 16) & 1)) >> 16;   // RNE
    return (unsigned short)u;
}

// ---------------- prep kernels ----------------

__global__ __launch_bounds__(256) void convx(const float* __restrict__ X,
                                             unsigned short* __restrict__ O) {
    int i = blockIdx.x * 256 + threadIdx.x;
    float4 v = ((const float4*)X)[i];
    us4 o;
    o.x = f2bf(v.x); o.y = f2bf(v.y); o.z = f2bf(v.z); o.w = f2bf(v.w);
    ((us4*)O)[i] = o;
}

// W [Kd][Cd] fp32  ->  WT [Cd][Kd] bf16
__global__ __launch_bounds__(256) void transposew(const float* __restrict__ W,
                                                  unsigned short* __restrict__ WT,
                                                  int Kd, int Cd) {
    __shared__ float t[32][33];
    int c0 = blockIdx.x * 32, k0 = blockIdx.y * 32;
    int tx = threadIdx.x & 31, ty = threadIdx.x >> 5;  // ty 0..7
#pragma unroll
    for (int i = 0; i < 32; i += 8)
        t[ty + i][tx] = W[(size_t)(k0 + ty + i) * Cd + c0 + tx];
    __syncthreads();
#pragma unroll
    for (int i = 0; i < 32; i += 8)
        WT[(size_t)(c0 + ty + i) * Kd + k0 + tx] = f2bf(t[tx][ty + i]);
}

// mask int32 0/1 -> byte array m8[flat] = mask[flat]  (round-1 proven)
__global__ __launch_bounds__(256) void packmask(const int* __restrict__ Mi,
                                                unsigned int* __restrict__ Mo) {
    int i = blockIdx.x * 256 + threadIdx.x;
    int4 v = ((const int4*)Mi)[i];
    Mo[i] = (unsigned)(v.x & 1) | ((unsigned)(v.y & 1) << 8) |
            ((unsigned)(v.z & 1) << 16) | ((unsigned)(v.w & 1) << 24);
}

// ---------------- GEMM: C = A[M][K] * BT[N][K]^T ----------------
template <int MODE>
__global__ __launch_bounds__(256) void gemm_bf16(
    const unsigned short* __restrict__ A, const unsigned short* __restrict__ BT,
    int M, int N, int K,
    unsigned short* __restrict__ Qo, unsigned short* __restrict__ Ko,
    unsigned short* __restrict__ Vo,
    const float* __restrict__ bias, float* __restrict__ Co) {
    __shared__ unsigned short Asub[128 * 64];
    __shared__ unsigned short Bsub[128 * 64];
    const int bm = blockIdx.y, bn = blockIdx.x;
    const int tid = threadIdx.x, w = tid >> 6, lane = tid & 63;
    const int wr = w >> 1, wc = w & 1, l16 = lane & 15, lg = lane >> 4;

    f32x4 acc[4][4];
#pragma unroll
    for (int i = 0; i < 4; i++)
#pragma unroll
        for (int j = 0; j < 4; j++) acc[i][j] = (f32x4){0.f, 0.f, 0.f, 0.f};

    const int r_st = tid >> 3;
    const int kc_st = (tid & 7) * 8;

    const int nkt = K / 64;
    for (int kt = 0; kt < nkt; kt++) {
        const int k0 = kt * 64;
#pragma unroll
        for (int i = 0; i < 4; i++) {
            int r = r_st + i * 32;
            uint4 va = *(const uint4*)(A + (size_t)(bm * 128 + r) * K + k0 + kc_st);
            uint4 vb = *(const uint4*)(BT + (size_t)(bn * 128 + r) * K + k0 + kc_st);
            int byt = (r * 128 + kc_st * 2) ^ ((r & 7) << 4);
            *(uint4*)((char*)Asub + byt) = va;
            *(uint4*)((char*)Bsub + byt) = vb;
        }
        __syncthreads();
#pragma unroll
        for (int ks = 0; ks < 2; ks++) {
            bf16x8 af[4], bfr[4];
            int kk = ks * 32 + lg * 8;
#pragma unroll
            for (int i = 0; i < 4; i++) {
                int r = wr * 64 + i * 16 + l16;
                af[i] = *(bf16x8*)((char*)Asub + ((r * 128 + kk * 2) ^ ((r & 7) << 4)));
                int c = wc * 64 + i * 16 + l16;
                bfr[i] = *(bf16x8*)((char*)Bsub + ((c * 128 + kk * 2) ^ ((c & 7) << 4)));
            }
#pragma unroll
            for (int i = 0; i < 4; i++)
#pragma unroll
                for (int j = 0; j < 4; j++)
                    acc[i][j] = __builtin_amdgcn_mfma_f32_16x16x32_bf16(
                        af[i], bfr[j], acc[i][j], 0, 0, 0);
        }
        __syncthreads();
    }

    if (MODE == 0) {
#pragma unroll
        for (int i = 0; i < 4; i++) {
            int grow = bm * 128 + wr * 64 + i * 16 + lg * 4;
            int bb = grow >> 11, ll = grow & 2047;
#pragma unroll
            for (int j = 0; j < 4; j++) {
                int gcol = bn * 128 + wc * 64 + j * 16 + l16;
                int s = gcol >> 10, hh = (gcol >> 6) & 15, dd = gcol & 63;
                int bhh = bb * 16 + hh;
                if (s == 2) {
                    us4 pk;
                    pk.x = f2bf(acc[i][j][0]); pk.y = f2bf(acc[i][j][1]);
                    pk.z = f2bf(acc[i][j][2]); pk.w = f2bf(acc[i][j][3]);
                    *(us4*)(Vo + (size_t)(bhh * 64 + dd) * 2048 + ll) = pk;
                } else {
                    unsigned short* dst =
                        (s == 0 ? Qo : Ko) + (size_t)(bhh * 2048 + ll) * 64 + dd;
#pragma unroll
                    for (int r = 0; r < 4; r++) dst[(size_t)r * 64] = f2bf(acc[i][j][r]);
                }
            }
        }
    } else {
#pragma unroll
        for (int i = 0; i < 4; i++) {
            int grow = bm * 128 + wr * 64 + i * 16 + lg * 4;
#pragma unroll
            for (int j = 0; j < 4; j++) {
                int gcol = bn * 128 + wc * 64 + j * 16 + l16;
                float bv = bias[gcol];
#pragma unroll
                for (int r = 0; r < 4; r++)
                    Co[(size_t)(grow + r) * N + gcol] = acc[i][j][r] + bv;
            }
        }
    }
}

// ---------------- flash attention (swapped QK^T; proven primitives only) ----
// grid: (qt=64, bh=32), block 128 = 2 waves, 16 q-rows each.
// Lane (l16,lg): q-row = qb+l16; after QK^T holds S^T[key=16j+4lg+r][q] in
// sacc[j][r]. Mask = m8 byte * fp32 multiply (round-1 mechanism). P packed
// with scalar f2bf (no cvtpk). Denominator = fp32 sum reduced through LDS.
__global__ __launch_bounds__(128) void flash_attn(
    const us* __restrict__ Q, const us* __restrict__ Kt,
    const us* __restrict__ VT, const unsigned char* __restrict__ M8,
    us* __restrict__ Z) {
    __shared__ char Plds[2 * 2048];
    __shared__ float Rs[2][4][16];
    const int bh = blockIdx.y;
    const int b = bh >> 4, h = bh & 15;
    const int tid = threadIdx.x, w = tid >> 6, lane = tid & 63;
    const int l16 = lane & 15, lg = lane >> 4;
    const int qb = blockIdx.x * 32 + w * 16;

    const us* Qp = Q + (size_t)(bh * 2048 + qb + l16) * 64 + lg * 8;
    bf16x8 qf0 = *(const bf16x8*)(Qp);
    bf16x8 qf1 = *(const bf16x8*)(Qp + 32);

    float m_r = -__builtin_inff();
    float l_r = 0.f;
    f32x4 oacc[4];
#pragma unroll
    for (int jd = 0; jd < 4; jd++) oacc[jd] = (f32x4){0.f, 0.f, 0.f, 0.f};

    char* pbase = Plds + w * 2048;
    const int sw = (l16 & 7) << 4;
    // this lane's q-row mask bytes; per (kt,j): 4 consecutive keys 16j+4lg+r
    const unsigned char* mrow = M8 + (size_t)(b * 2048 + qb + l16) * 2048 + 4 * lg;
    const size_t kbh = (size_t)bh * 2048;
    const size_t vbh = (size_t)bh * 64;

    for (int kt = 0; kt < 32; kt++) {
        const int lk0 = kt * 64;
        // ---- K fragments (A-operand of S^T = K·Q^T) ----
        bf16x8 kf[8];
#pragma unroll
        for (int j = 0; j < 4; j++) {
            const us* Kp = Kt + (size_t)(kbh + lk0 + j * 16 + l16) * 64 + lg * 8;
            kf[2 * j] = *(const bf16x8*)Kp;
            kf[2 * j + 1] = *(const bf16x8*)(Kp + 32);
        }
        uchar4 mu[4];
#pragma unroll
        for (int j = 0; j < 4; j++)
            mu[j] = *(const uchar4*)(mrow + lk0 + 16 * j);

        f32x4 sacc[4];
#pragma unroll
        for (int j = 0; j < 4; j++) sacc[j] = (f32x4){0.f, 0.f, 0.f, 0.f};
#pragma unroll
        for (int j = 0; j < 4; j++) {
            sacc[j] = __builtin_amdgcn_mfma_f32_16x16x32_bf16(kf[2 * j], qf0, sacc[j], 0, 0, 0);
            sacc[j] = __builtin_amdgcn_mfma_f32_16x16x32_bf16(kf[2 * j + 1], qf1, sacc[j], 0, 0, 0);
        }
        // ---- V fragments (A-operand of O^T = V^T·P) ----
        bf16x8 vf[8];
#pragma unroll
        for (int ks = 0; ks < 2; ks++)
#pragma unroll
            for (int jd = 0; jd < 4; jd++)
                vf[ks * 4 + jd] = *(const bf16x8*)(VT + (size_t)(vbh + jd * 16 + l16) * 2048 +
                                                   lk0 + ks * 32 + lg * 8);
        // ---- scaled scores; lane-local max over its 16 keys; lg-group max ----
        float ss[4][4];
#pragma unroll
        for (int j = 0; j < 4; j++)
#pragma unroll
            for (int r = 0; r < 4; r++) ss[j][r] = sacc[j][r] * SCALE;
        float mx0 = fmaxf(fmaxf(ss[0][0], ss[0][1]), fmaxf(ss[0][2], ss[0][3]));
        float mx1 = fmaxf(fmaxf(ss[1][0], ss[1][1]), fmaxf(ss[1][2], ss[1][3]));
        float mx2 = fmaxf(fmaxf(ss[2][0], ss[2][1]), fmaxf(ss[2][2], ss[2][3]));
        float mx3 = fmaxf(fmaxf(ss[3][0], ss[3][1]), fmaxf(ss[3][2], ss[3][3]));
        float mx = fmaxf(fmaxf(mx0, mx1), fmaxf(mx2, mx3));
        mx = fmaxf(mx, __shfl_xor(mx, 16));
        mx = fmaxf(mx, __shfl_xor(mx, 32));
        // (even if the cross-lane max were imperfect, it cancels in num/denom)
        float mn = fmaxf(m_r, mx);
        float alpha = __expf(m_r - mn);
        m_r = mn;
        float rs = 0.f;
#pragma unroll
        for (int j = 0; j < 4; j++) {
            float p0 = __expf(ss[j][0] - mn) * (float)mu[j].x;
            float p1 = __expf(ss[j][1] - mn) * (float)mu[j].y;
            float p2 = __expf(ss[j][2] - mn) * (float)mu[j].z;
            float p3 = __expf(ss[j][3] - mn) * (float)mu[j].w;
            rs += (p0 + p1) + (p2 + p3);
            uint2 pk;
            pk.x = (unsigned)f2bf(p0) | ((unsigned)f2bf(p1) << 16);
            pk.y = (unsigned)f2bf(p2) | ((unsigned)f2bf(p3) << 16);
            *(uint2*)(pbase + ((l16 * 128 + 32 * j + 8 * lg) ^ sw)) = pk;
        }
        Rs[w][lg][l16] = rs;
#pragma unroll
        for (int jd = 0; jd < 4; jd++) {
            oacc[jd][0] *= alpha; oacc[jd][1] *= alpha;
            oacc[jd][2] *= alpha; oacc[jd][3] *= alpha;
        }
        __syncthreads();   // P + Rs writes (cross-lane) visible
        l_r = l_r * alpha +
              ((Rs[w][0][l16] + Rs[w][1][l16]) + (Rs[w][2][l16] + Rs[w][3][l16]));
        // ---- PV ----
#pragma unroll
        for (int ks = 0; ks < 2; ks++) {
            bf16x8 pB = *(bf16x8*)(pbase + ((l16 * 128 + 64 * ks + 16 * lg) ^ sw));
#pragma unroll
            for (int jd = 0; jd < 4; jd++)
                oacc[jd] = __builtin_amdgcn_mfma_f32_16x16x32_bf16(vf[ks * 4 + jd], pB,
                                                                   oacc[jd], 0, 0, 0);
        }
        __syncthreads();   // reads done before next iter's writes
    }

    const float inv = 1.0f / (l_r + 1e-20f);
    us* zp = Z + (size_t)(b * 2048 + qb + l16) * 1024 + h * 64 + lg * 4;
#pragma unroll
    for (int jd = 0; jd < 4; jd++) {
        us4 pk;
        pk.x = f2bf(oacc[jd][0] * inv);
        pk.y = f2bf(oacc[jd][1] * inv);
        pk.z = f2bf(oacc[jd][2] * inv);
        pk.w = f2bf(oacc[jd][3] * inv);
        *(us4*)(zp + jd * 16) = pk;
    }
}

// ---------------- launcher ----------------

extern "C" void kernel_launch(void* const* d_in, const int* in_sizes, int n_in,
                              void* d_out, int out_size, void* d_ws, size_t ws_size,
                              hipStream_t stream) {
    const float* x = (const float*)d_in[0];
    const int* mask = (const int*)d_in[1];
    const float* Wqkv = (const float*)d_in[2];
    const float* Wout = (const float*)d_in[3];
    const float* bout = (const float*)d_in[4];
    float* out = (float*)d_out;
    char* ws = (char*)d_ws;

    // round-1's exact 48 MB layout (proven)
    unsigned short* xz    = (unsigned short*)(ws);               // 8 MB (x bf16, later Z bf16)
    unsigned short* wqkvT = (unsigned short*)(ws + (8u << 20));  // 6 MB
    unsigned short* woutT = (unsigned short*)(ws + (14u << 20)); // 2 MB
    unsigned char*  m8    = (unsigned char*)(ws + (16u << 20));  // 8 MB
    unsigned short* Qb    = (unsigned short*)(ws + (24u << 20)); // 8 MB
    unsigned short* Kb    = (unsigned short*)(ws + (32u << 20)); // 8 MB
    unsigned short* VTb   = (unsigned short*)(ws + (40u << 20)); // 8 MB

    convx<<<4096, 256, 0, stream>>>(x, xz);
    transposew<<<dim3(3072 / 32, 1024 / 32), 256, 0, stream>>>(Wqkv, wqkvT, 1024, 3072);
    transposew<<<dim3(1024 / 32, 1024 / 32), 256, 0, stream>>>(Wout, woutT, 1024, 1024);
    packmask<<<8192, 256, 0, stream>>>(mask, (unsigned int*)m8);
    gemm_bf16<0><<<dim3(3072 / 128, 4096 / 128), 256, 0, stream>>>(
        xz, wqkvT, 4096, 3072, 1024, Qb, Kb, VTb, nullptr, nullptr);
    flash_attn<<<dim3(64, 32), 128, 0, stream>>>(Qb, Kb, VTb, m8, xz);
    gemm_bf16<1><<<dim3(1024 / 128, 4096 / 128), 256, 0, stream>>>(
        xz, woutT, 4096, 1024, 1024, nullptr, nullptr, nullptr, bout, out);
}

// Round 6
// 374.543 us; speedup vs baseline: 1.0084x; 1.0084x over previous
//
#include <hip/hip_runtime.h>

typedef __attribute__((ext_vector_type(8))) short bf16x8;
typedef __attribute__((ext_vector_type(4))) float f32x4;
typedef __attribute__((ext_vector_type(4))) unsigned short us4;
typedef __attribute__((ext_vector_type(4))) unsigned int u32x4;
typedef unsigned short us;

#define SCALE 0.125f

__device__ __forceinline__ unsigned short f2bf(float f) {
    unsigned int u = __float_as_uint(f);
    u = (u + 0x7FFF + ((u >> 16) & 1)) >> 16;   // RNE
    return (unsigned short)u;
}

// ---------------- prep kernels ----------------

__global__ __launch_bounds__(256) void convx(const float* __restrict__ X,
                                             unsigned short* __restrict__ O) {
    int i = blockIdx.x * 256 + threadIdx.x;
    float4 v = ((const float4*)X)[i];
    us4 o;
    o.x = f2bf(v.x); o.y = f2bf(v.y); o.z = f2bf(v.z); o.w = f2bf(v.w);
    ((us4*)O)[i] = o;
}

// W [Kd][Cd] fp32  ->  WT [Cd][Kd] bf16
__global__ __launch_bounds__(256) void transposew(const float* __restrict__ W,
                                                  unsigned short* __restrict__ WT,
                                                  int Kd, int Cd) {
    __shared__ float t[32][33];
    int c0 = blockIdx.x * 32, k0 = blockIdx.y * 32;
    int tx = threadIdx.x & 31, ty = threadIdx.x >> 5;  // ty 0..7
#pragma unroll
    for (int i = 0; i < 32; i += 8)
        t[ty + i][tx] = W[(size_t)(k0 + ty + i) * Cd + c0 + tx];
    __syncthreads();
#pragma unroll
    for (int i = 0; i < 32; i += 8)
        WT[(size_t)(c0 + ty + i) * Kd + k0 + tx] = f2bf(t[tx][ty + i]);
}

// mask int32 0/1 -> byte array m8[flat] = mask[flat]  (round-1 proven)
__global__ __launch_bounds__(256) void packmask(const int* __restrict__ Mi,
                                                unsigned int* __restrict__ Mo) {
    int i = blockIdx.x * 256 + threadIdx.x;
    int4 v = ((const int4*)Mi)[i];
    Mo[i] = (unsigned)(v.x & 1) | ((unsigned)(v.y & 1) << 8) |
            ((unsigned)(v.z & 1) << 16) | ((unsigned)(v.w & 1) << 24);
}

// ---------------- GEMM: C = A[M][K] * BT[N][K]^T ----------------
template <int MODE>
__global__ __launch_bounds__(256) void gemm_bf16(
    const unsigned short* __restrict__ A, const unsigned short* __restrict__ BT,
    int M, int N, int K,
    unsigned short* __restrict__ Qo, unsigned short* __restrict__ Ko,
    unsigned short* __restrict__ Vo,
    const float* __restrict__ bias, float* __restrict__ Co) {
    __shared__ unsigned short Asub[128 * 64];
    __shared__ unsigned short Bsub[128 * 64];
    const int bm = blockIdx.y, bn = blockIdx.x;
    const int tid = threadIdx.x, w = tid >> 6, lane = tid & 63;
    const int wr = w >> 1, wc = w & 1, l16 = lane & 15, lg = lane >> 4;

    f32x4 acc[4][4];
#pragma unroll
    for (int i = 0; i < 4; i++)
#pragma unroll
        for (int j = 0; j < 4; j++) acc[i][j] = (f32x4){0.f, 0.f, 0.f, 0.f};

    const int r_st = tid >> 3;
    const int kc_st = (tid & 7) * 8;

    const int nkt = K / 64;
    for (int kt = 0; kt < nkt; kt++) {
        const int k0 = kt * 64;
#pragma unroll
        for (int i = 0; i < 4; i++) {
            int r = r_st + i * 32;
            uint4 va = *(const uint4*)(A + (size_t)(bm * 128 + r) * K + k0 + kc_st);
            uint4 vb = *(const uint4*)(BT + (size_t)(bn * 128 + r) * K + k0 + kc_st);
            int byt = (r * 128 + kc_st * 2) ^ ((r & 7) << 4);
            *(uint4*)((char*)Asub + byt) = va;
            *(uint4*)((char*)Bsub + byt) = vb;
        }
        __syncthreads();
#pragma unroll
        for (int ks = 0; ks < 2; ks++) {
            bf16x8 af[4], bfr[4];
            int kk = ks * 32 + lg * 8;
#pragma unroll
            for (int i = 0; i < 4; i++) {
                int r = wr * 64 + i * 16 + l16;
                af[i] = *(bf16x8*)((char*)Asub + ((r * 128 + kk * 2) ^ ((r & 7) << 4)));
                int c = wc * 64 + i * 16 + l16;
                bfr[i] = *(bf16x8*)((char*)Bsub + ((c * 128 + kk * 2) ^ ((c & 7) << 4)));
            }
#pragma unroll
            for (int i = 0; i < 4; i++)
#pragma unroll
                for (int j = 0; j < 4; j++)
                    acc[i][j] = __builtin_amdgcn_mfma_f32_16x16x32_bf16(
                        af[i], bfr[j], acc[i][j], 0, 0, 0);
        }
        __syncthreads();
    }

    if (MODE == 0) {
#pragma unroll
        for (int i = 0; i < 4; i++) {
            int grow = bm * 128 + wr * 64 + i * 16 + lg * 4;
            int bb = grow >> 11, ll = grow & 2047;
#pragma unroll
            for (int j = 0; j < 4; j++) {
                int gcol = bn * 128 + wc * 64 + j * 16 + l16;
                int s = gcol >> 10, hh = (gcol >> 6) & 15, dd = gcol & 63;
                int bhh = bb * 16 + hh;
                if (s == 2) {
                    us4 pk;
                    pk.x = f2bf(acc[i][j][0]); pk.y = f2bf(acc[i][j][1]);
                    pk.z = f2bf(acc[i][j][2]); pk.w = f2bf(acc[i][j][3]);
                    *(us4*)(Vo + (size_t)(bhh * 64 + dd) * 2048 + ll) = pk;
                } else {
                    unsigned short* dst =
                        (s == 0 ? Qo : Ko) + (size_t)(bhh * 2048 + ll) * 64 + dd;
#pragma unroll
                    for (int r = 0; r < 4; r++) dst[(size_t)r * 64] = f2bf(acc[i][j][r]);
                }
            }
        }
    } else {
#pragma unroll
        for (int i = 0; i < 4; i++) {
            int grow = bm * 128 + wr * 64 + i * 16 + lg * 4;
#pragma unroll
            for (int j = 0; j < 4; j++) {
                int gcol = bn * 128 + wc * 64 + j * 16 + l16;
                float bv = bias[gcol];
#pragma unroll
                for (int r = 0; r < 4; r++)
                    Co[(size_t)(grow + r) * N + gcol] = acc[i][j][r] + bv;
            }
        }
    }
}

// ---------------- flash attention (swapped QK^T; register-only exchange) ----
// grid: (qt=64, bh=32), block 128 = 2 waves, 16 q-rows each.
// Lane (l16,lg): q-row = qb+l16; after QK^T holds S^T[key=16j+4lg+r][q] in
// sacc[j][r]. P redistribution for PV is a 4-lane exchange at fixed l16:
// consumer (l16,lg) slot u needs pair W[2ks+(lg>>1)][u&1] from lane
// l16+16*((2lg+(u>>1))&3)  ->  16 __shfl + 8 cndmask per iter. No LDS, no
// barriers anywhere in the loop (the round-2/3 hazard class is gone).
__global__ __launch_bounds__(128) void flash_attn(
    const us* __restrict__ Q, const us* __restrict__ Kt,
    const us* __restrict__ VT, const unsigned char* __restrict__ M8,
    us* __restrict__ Z) {
    const int bh = blockIdx.y;
    const int b = bh >> 4, h = bh & 15;
    const int tid = threadIdx.x, w = tid >> 6, lane = tid & 63;
    const int l16 = lane & 15, lg = lane >> 4;
    const int qb = blockIdx.x * 32 + w * 16;

    const us* Qp = Q + (size_t)(bh * 2048 + qb + l16) * 64 + lg * 8;
    bf16x8 qf0 = *(const bf16x8*)(Qp);
    bf16x8 qf1 = *(const bf16x8*)(Qp + 32);

    float m_r = -__builtin_inff();
    float l_r = 0.f;
    f32x4 oacc[4];
#pragma unroll
    for (int jd = 0; jd < 4; jd++) oacc[jd] = (f32x4){0.f, 0.f, 0.f, 0.f};

    // exchange source lanes (loop-invariant)
    const int L0 = l16 + (((2 * lg) & 3) << 4);
    const int L1 = l16 + (((2 * lg + 1) & 3) << 4);
    const bool hi = (lg >> 1) != 0;

    // this lane's q-row mask bytes; per (kt,j): 4 consecutive keys 16j+4lg+r
    const unsigned char* mrow = M8 + (size_t)(b * 2048 + qb + l16) * 2048 + 4 * lg;
    const size_t kbh = (size_t)bh * 2048;
    const size_t vbh = (size_t)bh * 64;

    for (int kt = 0; kt < 32; kt++) {
        const int lk0 = kt * 64;
        // ---- K fragments (A-operand of S^T = K·Q^T) ----
        bf16x8 kf[8];
#pragma unroll
        for (int j = 0; j < 4; j++) {
            const us* Kp = Kt + (size_t)(kbh + lk0 + j * 16 + l16) * 64 + lg * 8;
            kf[2 * j] = *(const bf16x8*)Kp;
            kf[2 * j + 1] = *(const bf16x8*)(Kp + 32);
        }
        uchar4 mu[4];
#pragma unroll
        for (int j = 0; j < 4; j++)
            mu[j] = *(const uchar4*)(mrow + lk0 + 16 * j);

        f32x4 sacc[4];
#pragma unroll
        for (int j = 0; j < 4; j++) sacc[j] = (f32x4){0.f, 0.f, 0.f, 0.f};
#pragma unroll
        for (int j = 0; j < 4; j++) {
            sacc[j] = __builtin_amdgcn_mfma_f32_16x16x32_bf16(kf[2 * j], qf0, sacc[j], 0, 0, 0);
            sacc[j] = __builtin_amdgcn_mfma_f32_16x16x32_bf16(kf[2 * j + 1], qf1, sacc[j], 0, 0, 0);
        }
        // ---- V fragments (A-operand of O^T = V^T·P) ----
        bf16x8 vf[8];
#pragma unroll
        for (int ks = 0; ks < 2; ks++)
#pragma unroll
            for (int jd = 0; jd < 4; jd++)
                vf[ks * 4 + jd] = *(const bf16x8*)(VT + (size_t)(vbh + jd * 16 + l16) * 2048 +
                                                   lk0 + ks * 32 + lg * 8);
        // ---- scaled scores; lane-local max over its 16 keys; lg-group max ----
        float ss[4][4];
#pragma unroll
        for (int j = 0; j < 4; j++)
#pragma unroll
            for (int r = 0; r < 4; r++) ss[j][r] = sacc[j][r] * SCALE;
        float mx0 = fmaxf(fmaxf(ss[0][0], ss[0][1]), fmaxf(ss[0][2], ss[0][3]));
        float mx1 = fmaxf(fmaxf(ss[1][0], ss[1][1]), fmaxf(ss[1][2], ss[1][3]));
        float mx2 = fmaxf(fmaxf(ss[2][0], ss[2][1]), fmaxf(ss[2][2], ss[2][3]));
        float mx3 = fmaxf(fmaxf(ss[3][0], ss[3][1]), fmaxf(ss[3][2], ss[3][3]));
        float mx = fmaxf(fmaxf(mx0, mx1), fmaxf(mx2, mx3));
        mx = fmaxf(mx, __shfl_xor(mx, 16));
        mx = fmaxf(mx, __shfl_xor(mx, 32));
        float mn = fmaxf(m_r, mx);
        float alpha = __expf(m_r - mn);
        m_r = mn;
        // ---- p = exp(ss - mn) * mask; pack bf16 pair words W[j][rp] ----
        unsigned W[4][2];
        float rs = 0.f;
#pragma unroll
        for (int j = 0; j < 4; j++) {
            float p0 = __expf(ss[j][0] - mn) * (float)mu[j].x;
            float p1 = __expf(ss[j][1] - mn) * (float)mu[j].y;
            float p2 = __expf(ss[j][2] - mn) * (float)mu[j].z;
            float p3 = __expf(ss[j][3] - mn) * (float)mu[j].w;
            rs += (p0 + p1) + (p2 + p3);
            W[j][0] = (unsigned)f2bf(p0) | ((unsigned)f2bf(p1) << 16);
            W[j][1] = (unsigned)f2bf(p2) | ((unsigned)f2bf(p3) << 16);
        }
        rs += __shfl_xor(rs, 16);
        rs += __shfl_xor(rs, 32);
        l_r = l_r * alpha + rs;
#pragma unroll
        for (int jd = 0; jd < 4; jd++) {
            oacc[jd][0] *= alpha; oacc[jd][1] *= alpha;
            oacc[jd][2] *= alpha; oacc[jd][3] *= alpha;
        }
        // ---- register-only P exchange + PV ----
#pragma unroll
        for (int ks = 0; ks < 2; ks++) {
            unsigned a0 = __shfl((int)W[2 * ks][0], L0), b0 = __shfl((int)W[2 * ks + 1][0], L0);
            unsigned a1 = __shfl((int)W[2 * ks][1], L0), b1 = __shfl((int)W[2 * ks + 1][1], L0);
            unsigned a2 = __shfl((int)W[2 * ks][0], L1), b2 = __shfl((int)W[2 * ks + 1][0], L1);
            unsigned a3 = __shfl((int)W[2 * ks][1], L1), b3 = __shfl((int)W[2 * ks + 1][1], L1);
            u32x4 pw = (u32x4){hi ? b0 : a0, hi ? b1 : a1, hi ? b2 : a2, hi ? b3 : a3};
            bf16x8 pB = __builtin_bit_cast(bf16x8, pw);
#pragma unroll
            for (int jd = 0; jd < 4; jd++)
                oacc[jd] = __builtin_amdgcn_mfma_f32_16x16x32_bf16(vf[ks * 4 + jd], pB,
                                                                   oacc[jd], 0, 0, 0);
        }
    }

    const float inv = 1.0f / (l_r + 1e-20f);
    us* zp = Z + (size_t)(b * 2048 + qb + l16) * 1024 + h * 64 + lg * 4;
#pragma unroll
    for (int jd = 0; jd < 4; jd++) {
        us4 pk;
        pk.x = f2bf(oacc[jd][0] * inv);
        pk.y = f2bf(oacc[jd][1] * inv);
        pk.z = f2bf(oacc[jd][2] * inv);
        pk.w = f2bf(oacc[jd][3] * inv);
        *(us4*)(zp + jd * 16) = pk;
    }
}

// ---------------- launcher ----------------

extern "C" void kernel_launch(void* const* d_in, const int* in_sizes, int n_in,
                              void* d_out, int out_size, void* d_ws, size_t ws_size,
                              hipStream_t stream) {
    const float* x = (const float*)d_in[0];
    const int* mask = (const int*)d_in[1];
    const float* Wqkv = (const float*)d_in[2];
    const float* Wout = (const float*)d_in[3];
    const float* bout = (const float*)d_in[4];
    float* out = (float*)d_out;
    char* ws = (char*)d_ws;

    // round-1's exact 48 MB layout (proven)
    unsigned short* xz    = (unsigned short*)(ws);               // 8 MB (x bf16, later Z bf16)
    unsigned short* wqkvT = (unsigned short*)(ws + (8u << 20));  // 6 MB
    unsigned short* woutT = (unsigned short*)(ws + (14u << 20)); // 2 MB
    unsigned char*  m8    = (unsigned char*)(ws + (16u << 20));  // 8 MB
    unsigned short* Qb    = (unsigned short*)(ws + (24u << 20)); // 8 MB
    unsigned short* Kb    = (unsigned short*)(ws + (32u << 20)); // 8 MB
    unsigned short* VTb   = (unsigned short*)(ws + (40u << 20)); // 8 MB

    convx<<<4096, 256, 0, stream>>>(x, xz);
    transposew<<<dim3(3072 / 32, 1024 / 32), 256, 0, stream>>>(Wqkv, wqkvT, 1024, 3072);
    transposew<<<dim3(1024 / 32, 1024 / 32), 256, 0, stream>>>(Wout, woutT, 1024, 1024);
    packmask<<<8192, 256, 0, stream>>>(mask, (unsigned int*)m8);
    gemm_bf16<0><<<dim3(3072 / 128, 4096 / 128), 256, 0, stream>>>(
        xz, wqkvT, 4096, 3072, 1024, Qb, Kb, VTb, nullptr, nullptr);
    flash_attn<<<dim3(64, 32), 128, 0, stream>>>(Qb, Kb, VTb, m8, xz);
    gemm_bf16<1><<<dim3(1024 / 128, 4096 / 128), 256, 0, stream>>>(
        xz, woutT, 4096, 1024, 1024, nullptr, nullptr, nullptr, bout, out);
}